// Round 11
// baseline (481.138 us; speedup 1.0000x reference)
//
#include <hip/hip_runtime.h>
#include <hip/hip_bf16.h>

// Problem constants (match reference setup_inputs)
#define NN 30000      // nodes
#define NE 600000     // edges
#define DD 128        // feature dim
#define RR 7          // relations
#define GG 16         // graphs
#define LL 3          // layers

#define NB64 ((NN + 63) / 64)   // 469 buckets of 64 nodes (sort granularity)
#define NROW (NB64 * 64)        // 30016 padded rows
#define NB32 (NROW / 32)        // 938 gemm3 blocks (32 rows each)
#define MS   (RR * DD)          // 896 msg row stride

typedef short bf16x8 __attribute__((ext_vector_type(8)));  // 8 bf16 = 4 VGPRs
typedef float f32x4  __attribute__((ext_vector_type(4)));

// ---- bf16 helpers ----------------------------------------------------------
__device__ __forceinline__ unsigned short f2bf(float f) {
    unsigned u = __float_as_uint(f);
    unsigned r = (u + 0x7fffu + ((u >> 16) & 1u)) >> 16;
    return (unsigned short)r;
}
__device__ __forceinline__ ushort2 pk2bf(float a, float b) {
    __hip_bfloat162 t = __float22bfloat162_rn(make_float2(a, b));
    return *(ushort2*)&t;
}

// ---------------------------------------------------------------------------
// Weight pack: Bw2[l][kc][n][k'] (bf16) with B[k][n] = Wr[l][k][n] (k<896)
// else Wl[l][k-896][n];  k = kc*128 + k'. Also zeros bcnt (runs before hist).
// ---------------------------------------------------------------------------
__global__ __launch_bounds__(256) void pack_weights(
    const float* __restrict__ Wl,   // L x 128 x 128
    const float* __restrict__ Wr,   // L x 896 x 128
    unsigned short* __restrict__ Bw2,// L x 8 x 128 x 128
    int* __restrict__ bcnt)
{
    int t = blockIdx.x * 256 + threadIdx.x;
    if (t < NB64 * 16) bcnt[t] = 0;
    if (t >= LL * 8 * DD * DD) return;
    int kp = t & 127;
    int n  = (t >> 7) & 127;
    int kc = (t >> 14) & 7;
    int l  = t >> 17;
    int k  = kc * 128 + kp;
    float v;
    if (k < MS) v = Wr[(size_t)l * MS * DD + (size_t)k * DD + n];
    else        v = Wl[(size_t)l * DD * DD + (size_t)(k - MS) * DD + n];
    Bw2[(size_t)l * 8 * DD * DD + (size_t)kc * DD * DD + n * DD + kp] = f2bf(v);
}

// x (fp32) -> bf16; block 0 zeros gf; ALSO does the bucket histogram (merged
// to save a dispatch; bcnt zeroed by pack_weights which runs just before).
__global__ __launch_bounds__(256) void convert_bf16(
    const float* __restrict__ in, unsigned short* __restrict__ out,
    float* __restrict__ gf,
    const int* __restrict__ node_out, int* __restrict__ bcnt,
    int n4, int E)
{
    int i = blockIdx.x * 256 + threadIdx.x;
    if (blockIdx.x == 0) {
#pragma unroll
        for (int j = 0; j < 8; ++j) gf[threadIdx.x + j * 256] = 0.f;
    }
    if (i < E) atomicAdd(&bcnt[(node_out[i] >> 6) * 16], 1);
    if (i >= n4) return;
    float4 v = ((const float4*)in)[i];
    ushort2 lo = pk2bf(v.x, v.y);
    ushort2 hi = pk2bf(v.z, v.w);
    ((ushort4*)out)[i] = make_ushort4(lo.x, lo.y, hi.x, hi.y);
}

// ---------------------------------------------------------------------------
// Bucketed edge sort. Bucket = 64 dest nodes; within bucket sort by
// key = (dest&63)<<3 | rel (512 bins). Emits meta=((src<<7)|rel, ew) grouped
// by (dest,rel) and start2[node*8 + r] (slot 7 = end of node's edges).
// ---------------------------------------------------------------------------
__global__ __launch_bounds__(512) void bucket_scan(
    const int* __restrict__ bcnt, int* __restrict__ bstart,
    int* __restrict__ bcur, int nb)
{
    __shared__ int s[512];
    int t = threadIdx.x;
    int v = (t < nb) ? bcnt[t * 16] : 0;
    s[t] = v;
    __syncthreads();
#pragma unroll
    for (int off = 1; off < 512; off <<= 1) {
        int u = (t >= off) ? s[t - off] : 0;
        __syncthreads();
        s[t] += u;
        __syncthreads();
    }
    if (t <= nb) {
        int excl = s[t] - v;
        bstart[t] = excl;
        if (t < nb) bcur[t * 16] = excl;
    }
}

// pack.x = (out&63)<<21 | rel<<18 | src   (src < 2^18)
__global__ __launch_bounds__(256) void bucket_scatter(
    const int* __restrict__ node_in,
    const int* __restrict__ node_out,
    const int* __restrict__ relation,
    const float* __restrict__ ew,
    int* __restrict__ bcur,
    int2* __restrict__ tmp,
    int E)
{
    int e = blockIdx.x * 256 + threadIdx.x;
    if (e >= E) return;
    int o = node_out[e];
    int pos = atomicAdd(&bcur[(o >> 6) * 16], 1);
    tmp[pos] = make_int2(((o & 63) << 21) | (relation[e] << 18) | node_in[e],
                         __float_as_int(ew[e]));
}

__global__ __launch_bounds__(256) void bucket_sort(
    const int2* __restrict__ tmp,
    const int* __restrict__ bstart,
    int2* __restrict__ meta,
    int* __restrict__ start2,   // NROW*8
    int N)
{
    __shared__ int hist[512];
    __shared__ int excl[512];
    __shared__ int cur[512];
    __shared__ int ssum[256];
    const int b = blockIdx.x;
    const int t = threadIdx.x;
    const int s0 = bstart[b];
    const int s1 = bstart[b + 1];

    hist[t] = 0; hist[t + 256] = 0;
    __syncthreads();
    for (int i = s0 + t; i < s1; i += 256)
        atomicAdd(&hist[((unsigned)tmp[i].x) >> 18], 1);
    __syncthreads();

    int a0 = hist[2 * t], a1 = hist[2 * t + 1];
    ssum[t] = a0 + a1;
    __syncthreads();
#pragma unroll
    for (int off = 1; off < 256; off <<= 1) {
        int u = (t >= off) ? ssum[t - off] : 0;
        __syncthreads();
        ssum[t] += u;
        __syncthreads();
    }
    int base = (t == 0) ? 0 : ssum[t - 1];
    excl[2 * t] = base;
    excl[2 * t + 1] = base + a0;
    cur[2 * t] = s0 + base;
    cur[2 * t + 1] = s0 + base + a0;
    __syncthreads();

    {
        // write start2 for ALL 64 local nodes (pad nodes get empty ranges)
        int k0 = 2 * t, k1 = 2 * t + 1;
        int n0 = b * 64 + (k0 >> 3), n1 = b * 64 + (k1 >> 3);
        start2[n0 * 8 + (k0 & 7)] = s0 + excl[k0];
        start2[n1 * 8 + (k1 & 7)] = s0 + excl[k1];
    }
    __syncthreads();

    for (int i = s0 + t; i < s1; i += 256) {
        int2 m = tmp[i];
        int key = ((unsigned)m.x) >> 18;
        int pos = atomicAdd(&cur[key], 1);
        int src = m.x & 0x3ffff;
        int rel = key & 7;
        meta[pos] = make_int2((src << 7) | rel, m.y);
    }
}

// ---------------------------------------------------------------------------
// aggregate_msg: msg[d][r][:] = sum_{e in seg(d,r)} ew_e * h[src_e][:]
// TWO 64-lane waves per dest node (wave owns 64 of 128 cols, lane owns 1 col)
// -> 60k waves for 2x latency hiding. 7 fp32 accs/lane; flat edge loop
// (unroll 16 for MLP); rel routed via wave-uniform predicated fmaf chain.
// ---------------------------------------------------------------------------
__global__ __launch_bounds__(256) void aggregate_msg(
    const unsigned short* __restrict__ hb,   // NROW x 128 bf16
    const int* __restrict__ start2,          // NROW*8
    const int2* __restrict__ meta,           // E
    unsigned short* __restrict__ msg,        // NROW x 896 bf16
    int N)
{
    int gt  = blockIdx.x * 256 + threadIdx.x;
    int wid = gt >> 7;                        // node
    int col = gt & 127;                       // column 0..127
    if (wid >= N) return;

    int e0 = start2[wid * 8];
    int e1 = start2[wid * 8 + 7];

    float a0 = 0.f, a1 = 0.f, a2 = 0.f, a3 = 0.f, a4 = 0.f, a5 = 0.f, a6 = 0.f;

#define ACC1(MX, MY, US) {                                                   \
    float wt = __int_as_float(MY);                                           \
    float f = __uint_as_float(((unsigned)(US)) << 16);                       \
    int r = (MX) & 7;                                                        \
    if (r == 0)      a0 = fmaf(wt, f, a0);                                   \
    else if (r == 1) a1 = fmaf(wt, f, a1);                                   \
    else if (r == 2) a2 = fmaf(wt, f, a2);                                   \
    else if (r == 3) a3 = fmaf(wt, f, a3);                                   \
    else if (r == 4) a4 = fmaf(wt, f, a4);                                   \
    else if (r == 5) a5 = fmaf(wt, f, a5);                                   \
    else             a6 = fmaf(wt, f, a6); }

    int e = e0;
    for (; e + 16 <= e1; e += 16) {
        int2 m[16]; unsigned short u[16];
#pragma unroll
        for (int j = 0; j < 16; ++j) m[j] = meta[e + j];
#pragma unroll
        for (int j = 0; j < 16; ++j) u[j] = hb[(m[j].x & ~127) + col];
#pragma unroll
        for (int j = 0; j < 16; ++j) ACC1(m[j].x, m[j].y, u[j]);
    }
    for (; e + 4 <= e1; e += 4) {
        int2 m[4]; unsigned short u[4];
#pragma unroll
        for (int j = 0; j < 4; ++j) m[j] = meta[e + j];
#pragma unroll
        for (int j = 0; j < 4; ++j) u[j] = hb[(m[j].x & ~127) + col];
#pragma unroll
        for (int j = 0; j < 4; ++j) ACC1(m[j].x, m[j].y, u[j]);
    }
    for (; e < e1; ++e) {
        int2 m = meta[e];
        unsigned short u = hb[(m.x & ~127) + col];
        ACC1(m.x, m.y, u);
    }
#undef ACC1

    unsigned short* mrow = msg + (size_t)wid * MS + col;
    mrow[0 * DD] = f2bf(a0);
    mrow[1 * DD] = f2bf(a1);
    mrow[2 * DD] = f2bf(a2);
    mrow[3 * DD] = f2bf(a3);
    mrow[4 * DD] = f2bf(a4);
    mrow[5 * DD] = f2bf(a5);
    mrow[6 * DD] = f2bf(a6);
}

// ---------------------------------------------------------------------------
// gemm3: h' = relu([msg | h] (N x 1024) @ Bw2 (1024 x 128) + br + bl)
// 938 blocks x 256 threads (4 waves). Block owns 32 rows x 128 cols; K=1024
// in 8 chunks of 128. DOUBLE-buffered LDS A (1 barrier/chunk); A global loads
// issued at chunk start, committed to the other buffer at chunk end (latency
// hidden behind 16 MFMAs). B fragments software-pipelined one step ahead in
// registers from the L2-resident 256 KB packed weights.
// ---------------------------------------------------------------------------
#define ASTR3 136
__global__ __launch_bounds__(256) void gemm3(
    const unsigned short* __restrict__ msg,  // NROW x 896 bf16
    const unsigned short* __restrict__ hb,   // NROW x 128 bf16
    const unsigned short* __restrict__ Bw2l, // 8 x 128 x 128 bf16 (kc,n,k')
    const float* __restrict__ br,            // 128
    const float* __restrict__ bl,            // 128
    unsigned short* __restrict__ out_bf16,   // NROW x 128 or null
    float* __restrict__ out_f32,             // N x 128 or null
    int N)
{
    __shared__ unsigned short As[2][32 * ASTR3];   // 2 x 8704 B

    const int tid  = threadIdx.x;
    const int wave = tid >> 6;
    const int lane = tid & 63;
    const int quad = lane >> 4;
    const int l16  = lane & 15;
    const int row0 = blockIdx.x * 32;
    const int ncol = wave * 32 + l16;

    const int sr = tid >> 4;                 // 0..15 staging row (v0), +16 (v1)
    const int sc = tid & 15;                 // staging 16B-chunk within row

    f32x4 acc00 = (f32x4){0.f, 0.f, 0.f, 0.f};
    f32x4 acc01 = (f32x4){0.f, 0.f, 0.f, 0.f};
    f32x4 acc10 = (f32x4){0.f, 0.f, 0.f, 0.f};
    f32x4 acc11 = (f32x4){0.f, 0.f, 0.f, 0.f};

    // pre-stage chunk 0 (msg cols 0..127)
    {
        const unsigned short* asrc = msg + (size_t)row0 * MS;
        int4 v0 = *(const int4*)(asrc + (size_t)sr * MS + sc * 8);
        int4 v1 = *(const int4*)(asrc + (size_t)(sr + 16) * MS + sc * 8);
        *(int4*)(&As[0][sr * ASTR3 + sc * 8]) = v0;
        *(int4*)(&As[0][(sr + 16) * ASTR3 + sc * 8]) = v1;
    }
    __syncthreads();

    bf16x8 b0 = *(const bf16x8*)(Bw2l + (size_t)ncol * DD + quad * 8);
    bf16x8 b1 = *(const bf16x8*)(Bw2l + (size_t)(ncol + 16) * DD + quad * 8);
    int4 v0, v1;

#pragma unroll
    for (int t = 0; t < 32; ++t) {
        const int kc  = t >> 2;
        const int kci = t & 3;

        // issue next-chunk A loads at chunk start (waited at chunk end)
        if (kci == 0 && kc < 7) {
            const unsigned short* asrc;
            int astr;
            if (kc + 1 < 7) { asrc = msg + (size_t)row0 * MS + (kc + 1) * 128; astr = MS; }
            else            { asrc = hb  + (size_t)row0 * DD;                  astr = DD; }
            v0 = *(const int4*)(asrc + (size_t)sr * astr + sc * 8);
            v1 = *(const int4*)(asrc + (size_t)(sr + 16) * astr + sc * 8);
        }

        // B prefetch one step ahead
        bf16x8 nb0 = b0, nb1 = b1;
        if (t < 31) {
            const int nt = t + 1;
            const unsigned short* bp =
                Bw2l + (size_t)(nt >> 2) * (DD * DD) + (nt & 3) * 32 + quad * 8;
            nb0 = *(const bf16x8*)(bp + (size_t)ncol * DD);
            nb1 = *(const bf16x8*)(bp + (size_t)(ncol + 16) * DD);
        }

        const unsigned short* Ab = As[kc & 1];
        bf16x8 a0 = *(const bf16x8*)(Ab + l16 * ASTR3 + kci * 32 + quad * 8);
        bf16x8 a1 = *(const bf16x8*)(Ab + (16 + l16) * ASTR3 + kci * 32 + quad * 8);
        acc00 = __builtin_amdgcn_mfma_f32_16x16x32_bf16(a0, b0, acc00, 0, 0, 0);
        acc01 = __builtin_amdgcn_mfma_f32_16x16x32_bf16(a0, b1, acc01, 0, 0, 0);
        acc10 = __builtin_amdgcn_mfma_f32_16x16x32_bf16(a1, b0, acc10, 0, 0, 0);
        acc11 = __builtin_amdgcn_mfma_f32_16x16x32_bf16(a1, b1, acc11, 0, 0, 0);

        // commit next chunk to the other buffer + single barrier per chunk
        if (kci == 3 && kc < 7) {
            unsigned short* Aw = (unsigned short*)As[(kc + 1) & 1];
            *(int4*)(Aw + sr * ASTR3 + sc * 8) = v0;
            *(int4*)(Aw + (sr + 16) * ASTR3 + sc * 8) = v1;
            __syncthreads();
        }
        b0 = nb0; b1 = nb1;
    }

    float bias0 = br[ncol] + bl[ncol];
    float bias1 = br[ncol + 16] + bl[ncol + 16];
#pragma unroll
    for (int reg = 0; reg < 4; ++reg) {
        int r0 = row0 + quad * 4 + reg;
        int r1 = r0 + 16;
        float v00 = fmaxf(acc00[reg] + bias0, 0.f);
        float v01 = fmaxf(acc01[reg] + bias1, 0.f);
        float v10 = fmaxf(acc10[reg] + bias0, 0.f);
        float v11 = fmaxf(acc11[reg] + bias1, 0.f);
        if (out_bf16) {
            ushort2 p0 = pk2bf(v00, v01);
            ushort2 p1 = pk2bf(v10, v11);
            out_bf16[(size_t)r0 * DD + ncol]      = p0.x;
            out_bf16[(size_t)r0 * DD + ncol + 16] = p0.y;
            out_bf16[(size_t)r1 * DD + ncol]      = p1.x;
            out_bf16[(size_t)r1 * DD + ncol + 16] = p1.y;
        }
        if (out_f32) {
            if (r0 < N) {
                out_f32[(size_t)r0 * DD + ncol]      = v00;
                out_f32[(size_t)r0 * DD + ncol + 16] = v01;
            }
            if (r1 < N) {
                out_f32[(size_t)r1 * DD + ncol]      = v10;
                out_f32[(size_t)r1 * DD + ncol + 16] = v11;
            }
        }
    }
}

// ---------------------------------------------------------------------------
// Graph segment sum: gf[n2g[n]] += nf[n] (n2g sorted).
// ---------------------------------------------------------------------------
__global__ __launch_bounds__(256) void graph_sum(
    const float* __restrict__ nf,
    const int* __restrict__ n2g,
    float* __restrict__ gf,
    int N)
{
    int t = blockIdx.x * 256 + threadIdx.x;
    int chunk = t >> 5;
    int lane = t & 31;
    int n0 = chunk * 16;
    if (n0 >= N) return;
    int nend = n0 + 16; if (nend > N) nend = N;

    float4 acc = make_float4(0.f, 0.f, 0.f, 0.f);
    int curg = n2g[n0];
    for (int n = n0; n < nend; ++n) {
        int g = n2g[n];
        if (g != curg) {
            float* dst = gf + (size_t)curg * DD + lane * 4;
            atomicAdd(dst + 0, acc.x); atomicAdd(dst + 1, acc.y);
            atomicAdd(dst + 2, acc.z); atomicAdd(dst + 3, acc.w);
            acc = make_float4(0.f, 0.f, 0.f, 0.f);
            curg = g;
        }
        float4 v = *(const float4*)(nf + (size_t)n * DD + lane * 4);
        acc.x += v.x; acc.y += v.y; acc.z += v.z; acc.w += v.w;
    }
    float* dst = gf + (size_t)curg * DD + lane * 4;
    atomicAdd(dst + 0, acc.x); atomicAdd(dst + 1, acc.y);
    atomicAdd(dst + 2, acc.z); atomicAdd(dst + 3, acc.w);
}

// ---------------------------------------------------------------------------
extern "C" void kernel_launch(void* const* d_in, const int* in_sizes, int n_in,
                              void* d_out, int out_size, void* d_ws, size_t ws_size,
                              hipStream_t stream)
{
    const float* x        = (const float*)d_in[0];
    const int*   node_in  = (const int*)d_in[1];
    const int*   node_out = (const int*)d_in[2];
    const int*   relation = (const int*)d_in[3];
    const float* ew       = (const float*)d_in[4];
    const int*   n2g      = (const int*)d_in[5];
    const float* Wr       = (const float*)d_in[6];
    const float* br       = (const float*)d_in[7];
    const float* Wl       = (const float*)d_in[8];
    const float* bl       = (const float*)d_in[9];

    float* out = (float*)d_out;
    float* gf = out;                 // 16 x 128
    float* nf = out + GG * DD;       // 30000 x 128

    // Workspace layout (~82 MB)
    char* w = (char*)d_ws;
    unsigned short* msg  = (unsigned short*)w; w += (size_t)NROW * MS * 2;      // 53.8 MB
    unsigned short* hbA  = (unsigned short*)w; w += (size_t)NROW * DD * 2;      // 7.7 MB
    unsigned short* hbB  = (unsigned short*)w; w += (size_t)NROW * DD * 2;      // 7.7 MB
    unsigned short* Bw2  = (unsigned short*)w; w += (size_t)LL * 8 * DD * DD * 2; // 0.79 MB
    int2*  meta   = (int2*)w;                  w += (size_t)NE * 8;             // 4.8 MB
    int2*  tmp    = (int2*)w;                  w += (size_t)NE * 8;             // 4.8 MB
    int*   start2 = (int*)w;                   w += (size_t)NROW * 8 * 4;       // 0.96 MB
    int*   bcnt   = (int*)w;                   w += (size_t)NB64 * 16 * 4 + 64;
    int*   bcur   = (int*)w;                   w += (size_t)NB64 * 16 * 4 + 64;
    int*   bstart = (int*)w;                   w += (size_t)(NB64 + 1) * 4 + 60;

    const int N = NN, E = NE;

    // ---- once per call: pack (+bcnt zero), convert (+gf zero +hist), sort --
    pack_weights<<<(LL * 8 * DD * DD + 255) / 256, 256, 0, stream>>>(Wl, Wr, Bw2, bcnt);
    convert_bf16<<<(N * DD / 4 + 255) / 256, 256, 0, stream>>>(
        x, hbA, gf, node_out, bcnt, N * DD / 4, E);

    bucket_scan<<<1, 512, 0, stream>>>(bcnt, bstart, bcur, NB64);
    bucket_scatter<<<(E + 255) / 256, 256, 0, stream>>>(
        node_in, node_out, relation, ew, bcur, tmp, E);
    bucket_sort<<<NB64, 256, 0, stream>>>(tmp, bstart, meta, start2, N);

    // ---- layers ----
    unsigned short* hin = hbA;
    unsigned short* hnext = hbB;
    for (int l = 0; l < LL; ++l) {
        const float* br_l = br + (size_t)l * DD;
        const float* bl_l = bl + (size_t)l * DD;
        const unsigned short* Bw2_l = Bw2 + (size_t)l * 8 * DD * DD;

        aggregate_msg<<<(N * 128 + 255) / 256, 256, 0, stream>>>(
            hin, start2, meta, msg, N);

        bool last = (l == LL - 1);
        gemm3<<<NB32, 256, 0, stream>>>(
            msg, hin, Bw2_l, br_l, bl_l,
            last ? (unsigned short*)nullptr : hnext,
            last ? nf : (float*)nullptr, N);

        unsigned short* t = hin; hin = hnext; hnext = t;
    }

    // ---- graph_feature ----
    int chunks = (N + 15) / 16;
    graph_sum<<<(chunks * 32 + 255) / 256, 256, 0, stream>>>(nf, n2g, gf, N);
}